// Round 9
// baseline (300.487 us; speedup 1.0000x reference)
//
#include <hip/hip_runtime.h>

#define NNODES 50000
#define NFEAT 256
#define NHID 32
#define NHEADS 8
#define NCLASSES 32
#define NEDGES 800000
#define ETOT (NEDGES + NNODES)   // 850000 with self loops
#define NSCAN_BLK 196            // ceil(50000/256)
#define GEMM1_BLKS 782           // ceil(50000/64)
#define SCAT_BLKS 3321           // ceil(850000/256)

typedef __attribute__((ext_vector_type(8))) short short8;
typedef __attribute__((ext_vector_type(4))) float f32x4;

__device__ __forceinline__ void get_edge(const int* __restrict__ ei, int e,
                                         int& s, int& d) {
    if (e < NEDGES) { s = ei[e]; d = ei[NEDGES + e]; }
    else            { s = e - NEDGES; d = s; }
}
__device__ __forceinline__ float lrelu(float x) { return x > 0.f ? x : 0.2f * x; }
__device__ __forceinline__ unsigned short f2bf(float f) {   // RNE
    unsigned u = __float_as_uint(f);
    unsigned r = u + 0x7fffu + ((u >> 16) & 1u);
    return (unsigned short)(r >> 16);
}
__device__ __forceinline__ float bflo(unsigned u) { return __uint_as_float(u << 16); }
__device__ __forceinline__ float bfhi(unsigned u) { return __uint_as_float(u & 0xffff0000u); }

// ---------- fused: weight prep (blocks 0..35) + degree histogram (rest) ----------
__global__ void wprep_hist_k(const float* __restrict__ W1, const float* __restrict__ W2,
                             short8* __restrict__ W1frag, short8* __restrict__ W2frag,
                             const int* __restrict__ ei, int* __restrict__ deg) {
    if (blockIdx.x < 36) {
        int idx = blockIdx.x * 256 + threadIdx.x;
        if (idx < 8192) {
            int kc = idx >> 10, r = idx & 1023;
            int nt = r >> 6, lane = r & 63;
            int l16 = lane & 15, quad = lane >> 4;
            int n = nt * 16 + l16, k0 = kc * 32 + quad * 8;
            short8 v;
#pragma unroll
            for (int j = 0; j < 8; ++j) v[j] = (short)f2bf(W1[(k0 + j) * 256 + n]);
            W1frag[idx] = v;
        } else if (idx < 8192 + 1024) {
            int g = idx - 8192;
            int kc = g >> 7, r = g & 127;
            int nt = r >> 6, lane = r & 63;
            int l16 = lane & 15, quad = lane >> 4;
            int n = nt * 16 + l16, k0 = kc * 32 + quad * 8;
            short8 v;
#pragma unroll
            for (int j = 0; j < 8; ++j) v[j] = (short)f2bf(W2[(k0 + j) * 32 + n]);
            W2frag[g] = v;
        }
    } else {
        int e = (blockIdx.x - 36) * 256 + threadIdx.x;
        if (e >= ETOT) return;
        int s, d;
        get_edge(ei, e, s, d);
        atomicAdd(&deg[d], 1);
    }
}

// ---------- parallel scan, phase 1: per-block exclusive scan + block sums ----------
__global__ void scan_part_k(const int* __restrict__ deg, int* __restrict__ row_local,
                            int* __restrict__ bsum) {
    __shared__ int ws[4];
    int t = threadIdx.x, lane = t & 63, wid = t >> 6;
    int idx = blockIdx.x * 256 + t;
    int v = (idx < NNODES) ? deg[idx] : 0;
    int inc = v;
#pragma unroll
    for (int off = 1; off < 64; off <<= 1) {
        int u = __shfl_up(inc, off, 64);
        if (lane >= off) inc += u;
    }
    if (lane == 63) ws[wid] = inc;
    __syncthreads();
    int woff = 0;
#pragma unroll
    for (int j = 0; j < 4; ++j) woff += (j < wid) ? ws[j] : 0;
    if (idx < NNODES) row_local[idx] = woff + inc - v;
    if (t == 255) bsum[blockIdx.x] = woff + inc;
}

// ---------- scan phase 2+3 merged ----------
__global__ void scan_fix_k(const int* __restrict__ row_local, const int* __restrict__ bsum,
                           int* __restrict__ row_start) {
    __shared__ int ws[4];
    __shared__ int sboff;
    int t = threadIdx.x, lane = t & 63, wid = t >> 6;
    int v = (t < NSCAN_BLK) ? bsum[t] : 0;
    int inc = v;
#pragma unroll
    for (int off = 1; off < 64; off <<= 1) {
        int u = __shfl_up(inc, off, 64);
        if (lane >= off) inc += u;
    }
    if (lane == 63) ws[wid] = inc;
    __syncthreads();
    int woff = 0;
#pragma unroll
    for (int j = 0; j < 4; ++j) woff += (j < wid) ? ws[j] : 0;
    if (t == blockIdx.x) sboff = woff + inc - v;
    __syncthreads();
    int idx = blockIdx.x * 256 + t;
    if (idx < NNODES) row_start[idx] = row_local[idx] + sboff;
    if (idx == 0) row_start[NNODES] = ETOT;
}

// ---------- fused GEMM1 (MFMA bf16, direct coalesced global B) + attn1 + CSR scatter ----------
__global__ __launch_bounds__(256) void gemm1_scatter_k(
        const float* __restrict__ x, const short8* __restrict__ Wfrag,
        const float* __restrict__ av, const float* __restrict__ bv,
        unsigned short* __restrict__ z1, float* __restrict__ as_, float* __restrict__ ad_,
        const int* __restrict__ ei, const int* __restrict__ row_start,
        int* __restrict__ cursor, int* __restrict__ csr_src) {
    if (blockIdx.x >= GEMM1_BLKS) {
        int e = (blockIdx.x - GEMM1_BLKS) * 256 + threadIdx.x;
        if (e >= ETOT) return;
        int s, d;
        get_edge(ei, e, s, d);
        int pos = atomicAdd(&cursor[d], 1);
        csr_src[row_start[d] + pos] = s;
        return;
    }
    int t = threadIdx.x;
    int w = t >> 6, lane = t & 63;
    int quad = lane >> 4, l16 = lane & 15;
    int mA = blockIdx.x * 64 + w * 16 + l16;
    int mAl = min(mA, NNODES - 1);

    f32x4 acc[16];
#pragma unroll
    for (int nt = 0; nt < 16; ++nt) acc[nt] = (f32x4){0.f, 0.f, 0.f, 0.f};

#pragma unroll 2
    for (int kc = 0; kc < 8; ++kc) {
        int k0 = kc * 32 + quad * 8;
        const float4* xp = (const float4*)(x + (size_t)mAl * 256 + k0);
        float4 a0 = xp[0], a1 = xp[1];
        short8 af;
        af[0] = (short)f2bf(a0.x); af[1] = (short)f2bf(a0.y);
        af[2] = (short)f2bf(a0.z); af[3] = (short)f2bf(a0.w);
        af[4] = (short)f2bf(a1.x); af[5] = (short)f2bf(a1.y);
        af[6] = (short)f2bf(a1.z); af[7] = (short)f2bf(a1.w);
        // B-fragments: lane-consecutive 16-B slots -> fully coalesced, L2-resident
        short8 bfr[16];
#pragma unroll
        for (int nt = 0; nt < 16; ++nt) bfr[nt] = Wfrag[kc * 1024 + nt * 64 + lane];
#pragma unroll
        for (int nt = 0; nt < 16; ++nt)
            acc[nt] = __builtin_amdgcn_mfma_f32_16x16x32_bf16(af, bfr[nt], acc[nt], 0, 0, 0);
    }
    int mrow0 = blockIdx.x * 64 + w * 16 + quad * 4;
#pragma unroll
    for (int nt = 0; nt < 16; ++nt) {
        int n = nt * 16 + l16;
#pragma unroll
        for (int r = 0; r < 4; ++r) {
            int mr = mrow0 + r;
            if (mr < NNODES) z1[(size_t)mr * 256 + n] = f2bf(acc[nt][r]);
        }
    }
#pragma unroll
    for (int h = 0; h < 8; ++h) {
        float av0 = av[(2 * h) * 16 + l16], av1v = av[(2 * h + 1) * 16 + l16];
        float bv0 = bv[(2 * h) * 16 + l16], bv1v = bv[(2 * h + 1) * 16 + l16];
#pragma unroll
        for (int r = 0; r < 4; ++r) {
            float pa = acc[2 * h][r] * av0 + acc[2 * h + 1][r] * av1v;
            float pb = acc[2 * h][r] * bv0 + acc[2 * h + 1][r] * bv1v;
#pragma unroll
            for (int off = 1; off < 16; off <<= 1) {
                pa += __shfl_xor(pa, off, 64);
                pb += __shfl_xor(pb, off, 64);
            }
            int mr = mrow0 + r;
            if (l16 == 0 && mr < NNODES) { as_[mr * 8 + h] = pa; ad_[mr * 8 + h] = pb; }
        }
    }
}

// ---------- GEMM2 (MFMA bf16) + fused attn2 epilogue; z2 stored bf16 ----------
__global__ __launch_bounds__(256) void gemm2_mfma_k(
        const unsigned short* __restrict__ h1, const short8* __restrict__ Wfrag,
        const float* __restrict__ av, const float* __restrict__ bv,
        unsigned short* __restrict__ z2b, float* __restrict__ as_, float* __restrict__ ad_) {
    int w = threadIdx.x >> 6, lane = threadIdx.x & 63;
    int quad = lane >> 4, l16 = lane & 15;
    int mA = blockIdx.x * 64 + w * 16 + l16;
    int mAl = min(mA, NNODES - 1);

    f32x4 acc[2];
    acc[0] = (f32x4){0.f, 0.f, 0.f, 0.f};
    acc[1] = (f32x4){0.f, 0.f, 0.f, 0.f};
    for (int kc = 0; kc < 8; ++kc) {
        int k0 = kc * 32 + quad * 8;
        short8 af = *(const short8*)(h1 + (size_t)mAl * 256 + k0);
#pragma unroll
        for (int nt = 0; nt < 2; ++nt) {
            short8 bf8 = Wfrag[kc * 128 + nt * 64 + lane];
            acc[nt] = __builtin_amdgcn_mfma_f32_16x16x32_bf16(af, bf8, acc[nt], 0, 0, 0);
        }
    }
    int mrow0 = blockIdx.x * 64 + w * 16 + quad * 4;
    float av0 = av[l16], av1v = av[16 + l16];
    float bv0 = bv[l16], bv1v = bv[16 + l16];
#pragma unroll
    for (int r = 0; r < 4; ++r) {
        int mr = mrow0 + r;
        float pa = acc[0][r] * av0 + acc[1][r] * av1v;
        float pb = acc[0][r] * bv0 + acc[1][r] * bv1v;
#pragma unroll
        for (int off = 1; off < 16; off <<= 1) {
            pa += __shfl_xor(pa, off, 64);
            pb += __shfl_xor(pb, off, 64);
        }
        if (mr < NNODES) {
            z2b[(size_t)mr * 32 + l16] = f2bf(acc[0][r]);
            z2b[(size_t)mr * 32 + 16 + l16] = f2bf(acc[1][r]);
            if (l16 == 0) { as_[mr] = pa; ad_[mr] = pb; }
        }
    }
}

// ---------- fused layer-1 aggregation: one wave per dst, 8-deep, shuffle-deduped ----------
__global__ void agg1_csr_k(const int* __restrict__ row_start, const int* __restrict__ csr_src,
                           const unsigned short* __restrict__ z, const float* __restrict__ as_,
                           const float* __restrict__ ad_, const float* __restrict__ b,
                           unsigned short* __restrict__ h1) {
    int wv = threadIdx.x >> 6, lane = threadIdx.x & 63;
    int d = blockIdx.x * 4 + wv;
    int h = lane >> 3;
    int c0 = lane * 4;
    int e8 = lane & 7;
    float adh = ad_[d * 8 + h];
    int beg = row_start[d], end = row_start[d + 1];
    float sum = 0.f, a0 = 0.f, a1 = 0.f, a2 = 0.f, a3 = 0.f;
    int i = beg;
    for (; i + 8 <= end; i += 8) {
        int sv = csr_src[i + e8];
        float myw = __expf(lrelu(as_[sv * 8 + h] + adh));
        int se[8];
        float we[8];
#pragma unroll
        for (int e = 0; e < 8; ++e) {
            se[e] = __shfl(sv, e, 64);
            we[e] = __shfl(myw, (lane & 56) | e, 64);
        }
        uint2 q[8];
#pragma unroll
        for (int e = 0; e < 8; ++e)
            q[e] = *(const uint2*)(z + (size_t)se[e] * 256 + c0);
#pragma unroll
        for (int e = 0; e < 8; ++e) {
            float wgt = we[e];
            sum += wgt;
            a0 += wgt * bflo(q[e].x);
            a1 += wgt * bfhi(q[e].x);
            a2 += wgt * bflo(q[e].y);
            a3 += wgt * bfhi(q[e].y);
        }
    }
    for (; i < end; ++i) {
        int s = csr_src[i];
        float wgt = __expf(lrelu(as_[s * 8 + h] + adh));
        uint2 zz = *(const uint2*)(z + (size_t)s * 256 + c0);
        sum += wgt;
        a0 += wgt * bflo(zz.x);
        a1 += wgt * bfhi(zz.x);
        a2 += wgt * bflo(zz.y);
        a3 += wgt * bfhi(zz.y);
    }
    float inv = 1.f / sum;
    float o0 = a0 * inv + b[c0 + 0];
    float o1 = a1 * inv + b[c0 + 1];
    float o2 = a2 * inv + b[c0 + 2];
    float o3 = a3 * inv + b[c0 + 3];
    o0 = o0 > 0.f ? o0 : expm1f(o0);
    o1 = o1 > 0.f ? o1 : expm1f(o1);
    o2 = o2 > 0.f ? o2 : expm1f(o2);
    o3 = o3 > 0.f ? o3 : expm1f(o3);
    uint2 pk;
    pk.x = (unsigned)f2bf(o0) | ((unsigned)f2bf(o1) << 16);
    pk.y = (unsigned)f2bf(o2) | ((unsigned)f2bf(o3) << 16);
    *(uint2*)(h1 + (size_t)d * 256 + c0) = pk;
}

// ---------- fused layer-2 aggregation + bias: 16 lanes/dst, 2 bf16 ch/lane ----------
__global__ void agg2_csr_k(const int* __restrict__ row_start, const int* __restrict__ csr_src,
                           const unsigned short* __restrict__ z2b, const float* __restrict__ as_,
                           const float* __restrict__ ad_, const float* __restrict__ b,
                           float* __restrict__ out) {
    int g = blockIdx.x * 16 + (threadIdx.x >> 4);
    int l = threadIdx.x & 15;
    int lane = threadIdx.x & 63;
    int c0 = l * 2;
    int beg = row_start[g], end = row_start[g + 1];
    float adn = ad_[g];
    int e8 = l & 7;
    int gb = lane & 48;
    float sum = 0.f, a0 = 0.f, a1 = 0.f;
    int i = beg;
    for (; i + 8 <= end; i += 8) {
        int sv = csr_src[i + e8];
        float myw = __expf(lrelu(as_[sv] + adn));
        int se[8];
        float we[8];
#pragma unroll
        for (int e = 0; e < 8; ++e) {
            se[e] = __shfl(sv, gb | e, 64);
            we[e] = __shfl(myw, gb | (8 | e), 64);
        }
        unsigned q[8];
#pragma unroll
        for (int e = 0; e < 8; ++e)
            q[e] = *(const unsigned*)(z2b + (size_t)se[e] * 32 + c0);
#pragma unroll
        for (int e = 0; e < 8; ++e) {
            float wgt = we[e];
            sum += wgt;
            a0 += wgt * bflo(q[e]);
            a1 += wgt * bfhi(q[e]);
        }
    }
    for (; i < end; ++i) {
        int s = csr_src[i];
        float wgt = __expf(lrelu(as_[s] + adn));
        unsigned q = *(const unsigned*)(z2b + (size_t)s * 32 + c0);
        sum += wgt;
        a0 += wgt * bflo(q);
        a1 += wgt * bfhi(q);
    }
    float inv = 1.f / sum;
    float2 o;
    o.x = a0 * inv + b[c0];
    o.y = a1 * inv + b[c0 + 1];
    *(float2*)(out + (size_t)g * 32 + c0) = o;
}

extern "C" void kernel_launch(void* const* d_in, const int* in_sizes, int n_in,
                              void* d_out, int out_size, void* d_ws, size_t ws_size,
                              hipStream_t stream) {
    const float* x   = (const float*)d_in[0];
    const int*   ei  = (const int*)d_in[1];
    const float* W1  = (const float*)d_in[2];
    const float* av1 = (const float*)d_in[3];
    const float* bv1 = (const float*)d_in[4];
    const float* b1  = (const float*)d_in[5];
    const float* W2  = (const float*)d_in[6];
    const float* av2 = (const float*)d_in[7];
    const float* bv2 = (const float*)d_in[8];
    const float* b2  = (const float*)d_in[9];
    float* out = (float*)d_out;

    // workspace layout (4-byte units)
    unsigned short* z1 = (unsigned short*)d_ws;            // 12.8M bf16 = 6.4M u32
    unsigned short* h1 = (unsigned short*)((float*)d_ws + 6400000);  // 12.8M bf16
    float* as1 = (float*)d_ws + 12800000;                  // 400,000
    float* ad1 = as1 + 400000;                             // 400,000
    unsigned short* z2b = (unsigned short*)(ad1 + 400000); // 1.6M bf16 = 800,000 u32
    float* as2 = ad1 + 400000 + 800000;                    // 50,000
    float* ad2 = as2 + 50000;                              // 50,000
    short8* W1frag = (short8*)(ad2 + 50000);               // 8192 * 16 B
    short8* W2frag = W1frag + 8192;                        // 1024 * 16 B
    int* deg       = (int*)(ad2 + 50000) + 36864;          // 50,000
    int* cursor    = deg + 50000;                          // 50,000
    int* row_start = cursor + 50000;                       // 50,001
    int* csr_src   = row_start + 50001;                    // 850,000
    int* row_local = csr_src + 850000;                     // 50,000
    int* bsum      = row_local + 50000;                    // 256

    hipMemsetAsync(deg, 0, (size_t)100000 * 4, stream);    // deg + cursor

    // ---- weight prep + CSR build ----
    wprep_hist_k<<<36 + SCAT_BLKS, 256, 0, stream>>>(W1, W2, W1frag, W2frag, ei, deg);
    scan_part_k<<<NSCAN_BLK, 256, 0, stream>>>(deg, row_local, bsum);
    scan_fix_k<<<NSCAN_BLK, 256, 0, stream>>>(row_local, bsum, row_start);

    // ---- layer 1 (gemm1 fused with CSR scatter) ----
    gemm1_scatter_k<<<GEMM1_BLKS + SCAT_BLKS, 256, 0, stream>>>(
        x, W1frag, av1, bv1, z1, as1, ad1, ei, row_start, cursor, csr_src);
    agg1_csr_k<<<(NNODES + 3) / 4, 256, 0, stream>>>(row_start, csr_src, z1, as1, ad1, b1, h1);

    // ---- layer 2 ----
    gemm2_mfma_k<<<(NNODES + 63) / 64, 256, 0, stream>>>(h1, W2frag, av2, bv2, z2b, as2, ad2);
    agg2_csr_k<<<NNODES / 16, 256, 0, stream>>>(row_start, csr_src, z2b, as2, ad2, b2, out);
}